// Round 4
// baseline (154.382 us; speedup 1.0000x reference)
//
#include <hip/hip_runtime.h>

typedef __attribute__((ext_vector_type(8))) short bf16x8;
typedef __attribute__((ext_vector_type(4))) float f32x4;

__device__ __forceinline__ float bf2f(unsigned short u) {
  return __uint_as_float(((unsigned int)u) << 16);
}
__device__ __forceinline__ unsigned short f2bf(float f) {
  unsigned int u = __float_as_uint(f);
  u += 0x7fffu + ((u >> 16) & 1u);
  return (unsigned short)(u >> 16);
}

// ---------------- workspace layout (bytes) ----------------
constexpr size_t OFF_XPAD = 0;
constexpr size_t SZ_XPAD  = (size_t)8 * 66 * 66 * 128 * 2;        // 8,921,088
constexpr size_t OFF_WB   = OFF_XPAD + SZ_XPAD;
constexpr size_t SZ_WB    = (size_t)9 * 16 * 256 * 8 * 2;         // 589,824
constexpr size_t OFF_WS2  = OFF_WB + SZ_WB;
constexpr size_t SZ_WS2   = (size_t)16 * 256 * 8 * 2;             // 65,536
constexpr size_t OFF_WO   = OFF_WS2 + SZ_WS2;
constexpr size_t SZ_WO    = (size_t)9 * 16 * 32 * 8 * 2;          // 73,728
// y_main bf16 [32768][256]
constexpr size_t OFF_YM   = OFF_WO + SZ_WO;
constexpr size_t SZ_YM    = (size_t)32768 * 256 * 2;              // 16,777,216
constexpr size_t OFF_PART = OFF_YM + SZ_YM;
constexpr size_t SZ_PART  = (size_t)512 * 256 * 2 * 4;            // 1,048,576
constexpr size_t OFF_STAT = OFF_PART + SZ_PART;

// XCD swizzle: xcd = blockIdx.x % 8 (round-robin). b = blk&7 -> batch b lands on
// XCD b; per-XCD L2 working set = 1 batch xpad (1.1MB) + wB (0.58MB). Verified R2:
// FETCH_SIZE 26.4MB -> 7.3MB.

// ---------------- fused: x prep (blocks 0..511) + weight pack (blocks 512..1935) ----------------
// x-prep: single-barrier 128x68 bf16 LDS transpose (was 16 barriers through 16x66 tile).
__global__ __launch_bounds__(256) void k_prep(const float* __restrict__ x,
                                              unsigned short* __restrict__ xp,
                                              const float* __restrict__ wdef,
                                              const float* __restrict__ wsc,
                                              const float* __restrict__ woff,
                                              unsigned short* __restrict__ wB,
                                              unsigned short* __restrict__ wS,
                                              unsigned short* __restrict__ wO) {
  int t = threadIdx.x;
  if (blockIdx.x >= 512) {            // ---- weight packing part ----
    int tid = (blockIdx.x - 512) * 256 + t;
    if (tid < 294912) {
      int k8 = tid & 7, n = (tid >> 3) & 255, kb = (tid >> 11) & 15, tap = tid >> 15;
      int c = kb * 8 + k8;
      wB[tid] = f2bf(wdef[((size_t)n * 128 + c) * 9 + tap]);
    } else if (tid < 294912 + 32768) {
      int i = tid - 294912;
      int k8 = i & 7, n = (i >> 3) & 255, kb = i >> 11;
      wS[i] = f2bf(wsc[(size_t)n * 128 + kb * 8 + k8]);
    } else if (tid < 294912 + 32768 + 36864) {
      int i = tid - 327680;
      int k8 = i & 7, n = (i >> 3) & 31, kb = (i >> 8) & 15, tap = i >> 12;
      int c = kb * 8 + k8;
      wO[i] = f2bf(n < 18 ? woff[((size_t)n * 128 + c) * 9 + tap] : 0.f);
    }
    return;
  }
  // ---- x: NCHW fp32 -> NHWC bf16 zero-padded (+ halo zeroing, no memset) ----
  int blk = blockIdx.x;               // 512; b = blk&7 (XCD-local), h = blk>>3
  int b = blk & 7, h = blk >> 3;
  __shared__ unsigned short xt[128 * 68];   // [c][w], stride 68 (align + conflict-free cols)
  {
    unsigned short* base = xp + (size_t)b * 66 * 66 * 128;
    ushort4 z4 = {0, 0, 0, 0};
    if (t < 64) {                     // side columns of padded row h+1
      int col = (t >> 5) ? 65 : 0;
      int i = t & 31;
      *(ushort4*)(base + ((size_t)(h + 1) * 66 + col) * 128 + i * 4) = z4;
    }
    if (h == 0) {                     // top and bottom padded rows
      for (int i = t; i < 2112; i += 256) {
        *(ushort4*)(base + (size_t)i * 4) = z4;
        *(ushort4*)(base + (size_t)65 * 66 * 128 + (size_t)i * 4) = z4;
      }
    }
  }
  {
    // load: thread t -> c = t>>1, w0 = (t&1)*32: 32 contiguous floats -> bf16 -> LDS row
    int c = t >> 1, w0 = (t & 1) * 32;
    const float4* xs = (const float4*)&x[(((size_t)b * 128 + c) * 64 + h) * 64 + w0];
    unsigned short* row = &xt[c * 68 + w0];
#pragma unroll
    for (int i4 = 0; i4 < 8; ++i4) {
      float4 f = xs[i4];
      ushort4 u4;
      u4.x = f2bf(f.x); u4.y = f2bf(f.y); u4.z = f2bf(f.z); u4.w = f2bf(f.w);
      *(ushort4*)(row + i4 * 4) = u4;
    }
  }
  __syncthreads();
  {
    // store: thread t -> w = t>>2, c0 = (t&3)*32: column-gather 32 c, write 64B contig
    int w = t >> 2, c0 = (t & 3) * 32;
    unsigned short tmp[32];
#pragma unroll
    for (int i = 0; i < 32; ++i) tmp[i] = xt[(c0 + i) * 68 + w];
    unsigned short* dst = xp + ((size_t)(b * 66 + h + 1) * 66 + (w + 1)) * 128 + c0;
#pragma unroll
    for (int i8 = 0; i8 < 4; ++i8)
      *(bf16x8*)(dst + i8 * 8) = *(const bf16x8*)&tmp[i8 * 8];
  }
}

// ---------------- main: offset conv + deform-sample + 3x3 conv GEMM + BN partials ----------------
// 512 blocks x 512 thr (8 waves). KEY FIX vs r3: wB fragments for tap t are loaded into
// registers (Breg) at the END of tap t-1, so the MFMA cluster has ZERO vmcnt dependence
// (vmcnt is FIFO: consuming a wB load issued after the 8 gathers forced a full gather
// drain before the first MFMA). Gathers now have the whole MFMA+LDS span to complete.
__global__ __launch_bounds__(512, 4) void k_main(const unsigned short* __restrict__ xp,
                                                 const unsigned short* __restrict__ wB,
                                                 const unsigned short* __restrict__ wO,
                                                 const float* __restrict__ boff,
                                                 const float* __restrict__ bdef,
                                                 unsigned short* __restrict__ ymain,
                                                 float* __restrict__ partials) {
  int blk = blockIdx.x;               // 512; b = blk&7 (XCD-local), h = blk>>3
  int b = blk & 7, h = blk >> 3;
  int bh = (b << 6) + h;              // linear row id for ymain layout
  int t = threadIdx.x;
  int lane = t & 63, wid = t >> 6;    // 8 waves
  int m = lane & 15, quad = lane >> 4;
  __shared__ __align__(16) unsigned short At[2][64 * 136];  // 2 x 17408 B
  __shared__ float offsL[9][64][2];                          // 4608 B

  // ---- phase 0: inline offset conv (waves 0-3 compute this row's 18 offsets -> LDS) ----
  if (wid < 4) {
    f32x4 a0 = {0.f, 0.f, 0.f, 0.f}, a1 = {0.f, 0.f, 0.f, 0.f};
    int px = wid * 16 + m;
    const unsigned short* xbase = xp + ((size_t)(b * 66 + h) * 66 + px) * 128 + quad * 8;
    for (int tap = 0; tap < 9; ++tap) {
      const unsigned short* arow = xbase + ((tap / 3) * 66 + (tap % 3)) * 128;
#pragma unroll
      for (int kk = 0; kk < 4; ++kk) {
        bf16x8 a = *(const bf16x8*)(arow + kk * 32);
        const unsigned short* bb = wO + (size_t)(tap * 16 + kk * 4 + quad) * 256;
        bf16x8 b0 = *(const bf16x8*)(bb + m * 8);
        bf16x8 b1 = *(const bf16x8*)(bb + (16 + m) * 8);
        a0 = __builtin_amdgcn_mfma_f32_16x16x32_bf16(a, b0, a0, 0, 0, 0);
        a1 = __builtin_amdgcn_mfma_f32_16x16x32_bf16(a, b1, a1, 0, 0, 0);
      }
    }
#pragma unroll
    for (int r = 0; r < 4; ++r) {
      int pxs = wid * 16 + quad * 4 + r;
      offsL[m >> 1][pxs][m & 1] = a0[r] + boff[m];   // n=m in [0,16): tap=n>>1, comp=n&1
      if (m < 2) offsL[8][pxs][m] = a1[r] + boff[16 + m];
    }
  }

  f32x4 acc[4][2];
#pragma unroll
  for (int i = 0; i < 4; ++i)
#pragma unroll
    for (int j = 0; j < 2; ++j) acc[i][j] = (f32x4){0.f, 0.f, 0.f, 0.f};

  // sampling role: thread = px_s*8 + sub; 8 consecutive lanes cover one 128B chunk
  int px_s = t >> 3, sub = t & 7;
  const unsigned short* xb_base = xp + (size_t)b * 66 * 66 * 128;
  int nb = wid * 32;                  // mfma role: 32-ch N range per wave, M=64 shared

  bf16x8 Breg[4][2];                  // this tap's wB fragments, preloaded
  auto loadB = [&](int tap) {
#pragma unroll
    for (int kk = 0; kk < 4; ++kk)
#pragma unroll
      for (int ns = 0; ns < 2; ++ns)
        Breg[kk][ns] = *(const bf16x8*)(wB + ((size_t)(tap * 16 + kk * 4 + quad) * 256 + nb + ns * 16 + m) * 8);
  };

  auto sample_prep = [&](int tap, float* wgt, const unsigned short** p) {
    float2 ov = *(const float2*)&offsL[tap][px_s][0];
    int ky = tap / 3 - 1, kx = tap % 3 - 1;
    float py = (float)(h + ky) + ov.x;
    float pxf = (float)(px_s + kx) + ov.y;
    float y0f = floorf(py), x0f = floorf(pxf);
    float fy = py - y0f, fx = pxf - x0f;
    int iy0 = (int)y0f, ix0 = (int)x0f;
#pragma unroll
    for (int j = 0; j < 4; ++j) {
      int iy = iy0 + (j >> 1), ix = ix0 + (j & 1);
      float wy = (j >> 1) ? fy : 1.f - fy;
      float wx = (j & 1) ? fx : 1.f - fx;
      bool valid = (iy >= 0) && (iy < 64) && (ix >= 0) && (ix < 64);
      int iyc = min(max(iy, 0), 63), ixc = min(max(ix, 0), 63);
      wgt[j] = valid ? wy * wx : 0.f;
      p[j] = xb_base + ((size_t)(iyc + 1) * 66 + (ixc + 1)) * 128 + sub * 8;
    }
  };
  auto load_g1 = [&](const unsigned short** p, int g, bf16x8* v) {
#pragma unroll
    for (int j = 0; j < 4; ++j)
      v[j] = *(const bf16x8*)(p[j] + g * 64);
  };
  auto store_g1 = [&](unsigned short* dst, int g, const float* wgt, bf16x8* v) {
    bf16x8 o;
#pragma unroll
    for (int j = 0; j < 8; ++j) {
      float s = fmaf(wgt[0], bf2f((unsigned short)v[0][j]),
                fmaf(wgt[1], bf2f((unsigned short)v[1][j]),
                fmaf(wgt[2], bf2f((unsigned short)v[2][j]),
                     wgt[3] * bf2f((unsigned short)v[3][j]))));
      o[j] = (short)f2bf(s);
    }
    *(bf16x8*)(dst + g * 64) = o;
  };
  auto mfma_half = [&](const unsigned short* buf, int kk0) {
#pragma unroll
    for (int kk = kk0; kk < kk0 + 2; ++kk) {
      bf16x8 af[4];
#pragma unroll
      for (int ms = 0; ms < 4; ++ms)
        af[ms] = *(const bf16x8*)(buf + (ms * 16 + m) * 136 + kk * 32 + quad * 8);
#pragma unroll
      for (int ns = 0; ns < 2; ++ns)
#pragma unroll
        for (int ms = 0; ms < 4; ++ms)
          acc[ms][ns] = __builtin_amdgcn_mfma_f32_16x16x32_bf16(af[ms], Breg[kk][ns], acc[ms][ns], 0, 0, 0);
    }
  };

  // prologue: B-frags for tap 0 (oldest in vmem queue), then sample tap 0 into buf 0
  loadB(0);
  __syncthreads();                    // offsL ready
  {
    float wgt[4]; const unsigned short* p[4]; bf16x8 v0[4], v1[4];
    sample_prep(0, wgt, p);
    unsigned short* dst = &At[0][px_s * 136 + sub * 8];
    load_g1(p, 0, v0); load_g1(p, 1, v1);
    store_g1(dst, 0, wgt, v0); store_g1(dst, 1, wgt, v1);
  }
#pragma unroll
  for (int tap = 0; tap < 9; ++tap) {
    __syncthreads();
    const unsigned short* cur = At[tap & 1];
    unsigned short* dst = &At[(tap + 1) & 1][px_s * 136 + sub * 8];
    if (tap < 8) {
      float wgt[4]; const unsigned short* p[4]; bf16x8 v0[4], v1[4];
      sample_prep(tap + 1, wgt, p);
      load_g1(p, 0, v0);            // gathers issued (younger than nothing MFMA needs)
      load_g1(p, 1, v1);
      mfma_half(cur, 0);            // regs + ds_read only: no vmcnt dependence
      store_g1(dst, 0, wgt, v0);    // waits v0 (v1 still outstanding)
      mfma_half(cur, 2);
      loadB(tap + 1);               // prefetch next tap's B (returns during barrier+prep)
      store_g1(dst, 1, wgt, v1);
    } else {
      mfma_half(cur, 0);
      mfma_half(cur, 2);
    }
  }

  // ---- epilogue: bias + BN partials; LDS transpose -> coalesced bf16 stores ----
  __syncthreads();                    // all waves done reading At
  unsigned short* yb = &At[0][0];     // 64 x 264 bf16 (33792 B)
#pragma unroll
  for (int ns = 0; ns < 2; ++ns) {
    int n = nb + ns * 16 + m;
    float bias = bdef[n];
    float s = 0.f, q = 0.f;
#pragma unroll
    for (int ms = 0; ms < 4; ++ms) {
#pragma unroll
      for (int r = 0; r < 4; ++r) {
        int px = ms * 16 + quad * 4 + r;
        float v = acc[ms][ns][r] + bias;
        yb[px * 264 + n] = f2bf(v);
        s += v;
        q += v * v;
      }
    }
    s += __shfl_xor(s, 16); s += __shfl_xor(s, 32);
    q += __shfl_xor(q, 16); q += __shfl_xor(q, 32);
    if (quad == 0) {
      partials[((size_t)blk * 256 + n) * 2 + 0] = s;
      partials[((size_t)blk * 256 + n) * 2 + 1] = q;
    }
  }
  __syncthreads();
  {
    unsigned short* grow = ymain + (size_t)(bh * 64 + px_s) * 256;
    const unsigned short* lrow = yb + px_s * 264;
#pragma unroll
    for (int k = 0; k < 4; ++k) {
      int n0 = k * 64 + sub * 8;      // 8 consecutive lanes -> one 128B chunk
      __builtin_nontemporal_store(*(const bf16x8*)(lrow + n0), (bf16x8*)(grow + n0));
    }
  }
}

// ---------------- BN stats reduce ----------------
__global__ __launch_bounds__(64) void k_stats(const float* __restrict__ partials,
                                              const float* __restrict__ gamma,
                                              const float* __restrict__ beta,
                                              float* __restrict__ stats) {
  int ch = blockIdx.x;                // 256
  int L = threadIdx.x;                // 64
  float s = 0.f, q = 0.f;
#pragma unroll
  for (int i = 0; i < 8; ++i) {
    int row = i * 64 + L;
    float2 pq = *(const float2*)&partials[((size_t)row * 256 + ch) * 2];
    s += pq.x;
    q += pq.y;
  }
#pragma unroll
  for (int d = 1; d < 64; d <<= 1) { s += __shfl_xor(s, d); q += __shfl_xor(q, d); }
  if (L == 0) {
    float mean = s * (1.f / 32768.f);
    float var = q * (1.f / 32768.f) - mean * mean;
    float inv = rsqrtf(var + 1e-5f);
    float A = gamma[ch] * inv;
    stats[ch * 2 + 0] = A;
    stats[ch * 2 + 1] = beta[ch] - mean * A;
  }
}

// ---------------- final: 1x1 shortcut MFMA + BN apply + ReLU + NCHW store ----------------
// 1024 blocks x 32-px tiles -> 4 blocks/CU; batch->XCD swizzle; 4B/lane ymain reads.
__global__ __launch_bounds__(256) void k_final(const unsigned short* __restrict__ xp,
                                               const unsigned short* __restrict__ wS,
                                               const unsigned short* __restrict__ ymain,
                                               const float* __restrict__ stats,
                                               const float* __restrict__ bsc,
                                               float* __restrict__ out) {
  int blk = blockIdx.x;               // 1024; b = blk&7 (XCD-local)
  int b = blk & 7, rem = blk >> 3, h = rem >> 1, half = rem & 1;
  int px0 = half * 32;
  int bh = (b << 6) + h;
  int t = threadIdx.x;
  int lane = t & 63, wid = t >> 6;
  int m = lane & 15, quad = lane >> 4;
  __shared__ float tr[128 * 35];      // 17,920 B
  f32x4 acc[2][4];
#pragma unroll
  for (int i = 0; i < 2; ++i)
#pragma unroll
    for (int j = 0; j < 4; ++j) acc[i][j] = (f32x4){0.f, 0.f, 0.f, 0.f};
  const unsigned short* xrow = xp + ((size_t)(b * 66 + h + 1) * 66 + 1 + px0) * 128;
  int nb = wid * 64;
#pragma unroll
  for (int kk = 0; kk < 4; ++kk) {
    bf16x8 af[2];
#pragma unroll
    for (int ms = 0; ms < 2; ++ms)
      af[ms] = *(const bf16x8*)(xrow + (ms * 16 + m) * 128 + kk * 32 + quad * 8);
#pragma unroll
    for (int ns = 0; ns < 4; ++ns) {
      bf16x8 bfr = *(const bf16x8*)(wS + ((size_t)(kk * 4 + quad) * 256 + nb + ns * 16 + m) * 8);
#pragma unroll
      for (int ms = 0; ms < 2; ++ms)
        acc[ms][ns] = __builtin_amdgcn_mfma_f32_16x16x32_bf16(af[ms], bfr, acc[ms][ns], 0, 0, 0);
    }
  }
  for (int pass = 0; pass < 2; ++pass) {
    if ((wid >> 1) == pass) {
#pragma unroll
      for (int ns = 0; ns < 4; ++ns) {
        int n = nb + ns * 16 + m;
        float bs = bsc[n];
        int nl = n - pass * 128;
#pragma unroll
        for (int ms = 0; ms < 2; ++ms)
#pragma unroll
          for (int r = 0; r < 4; ++r) {
            int px = ms * 16 + quad * 4 + r;
            tr[nl * 35 + px] = acc[ms][ns][r] + bs;
          }
      }
    }
    __syncthreads();
    {
      int nl2 = t & 63, g = t >> 6;
      int n = pass * 128 + nl2 * 2;
      float A0 = stats[n * 2 + 0], B0 = stats[n * 2 + 1];
      float A1 = stats[n * 2 + 2], B1 = stats[n * 2 + 3];
#pragma unroll
      for (int i = 0; i < 8; ++i) {
        int pxl = g * 8 + i;
        unsigned int ym2 = *(const unsigned int*)(ymain + (size_t)(bh * 64 + px0 + pxl) * 256 + n);
        float y0 = bf2f((unsigned short)(ym2 & 0xffffu));
        float y1 = bf2f((unsigned short)(ym2 >> 16));
        int nl = nl2 * 2;
        float* p0 = &tr[nl * 35 + pxl];
        float* p1 = &tr[(nl + 1) * 35 + pxl];
        *p0 = fmaxf(fmaf(y0, A0, B0) + *p0, 0.f);
        *p1 = fmaxf(fmaf(y1, A1, B1) + *p1, 0.f);
      }
    }
    __syncthreads();
    {
      int ww = t & 31, ng = t >> 5;
#pragma unroll
      for (int i = 0; i < 16; ++i) {
        int nl = ng * 16 + i;
        out[((size_t)(b * 256 + pass * 128 + nl) * 64 + h) * 64 + px0 + ww] = tr[nl * 35 + ww];
      }
    }
    __syncthreads();
  }
}

extern "C" void kernel_launch(void* const* d_in, const int* in_sizes, int n_in,
                              void* d_out, int out_size, void* d_ws, size_t ws_size,
                              hipStream_t stream) {
  const float* x     = (const float*)d_in[0];
  const float* w_off = (const float*)d_in[1];
  const float* b_off = (const float*)d_in[2];
  const float* w_def = (const float*)d_in[3];
  const float* b_def = (const float*)d_in[4];
  const float* gamma = (const float*)d_in[5];
  const float* beta  = (const float*)d_in[6];
  const float* w_sc  = (const float*)d_in[7];
  const float* b_sc  = (const float*)d_in[8];
  float* out = (float*)d_out;

  char* ws = (char*)d_ws;
  unsigned short* xpad  = (unsigned short*)(ws + OFF_XPAD);
  unsigned short* wB    = (unsigned short*)(ws + OFF_WB);
  unsigned short* wS    = (unsigned short*)(ws + OFF_WS2);
  unsigned short* wO    = (unsigned short*)(ws + OFF_WO);
  unsigned short* ymain = (unsigned short*)(ws + OFF_YM);
  float* partials       = (float*)(ws + OFF_PART);
  float* stats          = (float*)(ws + OFF_STAT);

  k_prep<<<1936, 256, 0, stream>>>(x, xpad, w_def, w_sc, w_off, wB, wS, wO);
  k_main<<<512, 512, 0, stream>>>(xpad, wB, wO, b_off, b_def, ymain, partials);
  k_stats<<<256, 64, 0, stream>>>(partials, gamma, beta, stats);
  k_final<<<1024, 256, 0, stream>>>(xpad, wS, ymain, stats, b_sc, out);
}

// Round 6
// 149.520 us; speedup vs baseline: 1.0325x; 1.0325x over previous
//
#include <hip/hip_runtime.h>

typedef __attribute__((ext_vector_type(8))) short bf16x8;
typedef __attribute__((ext_vector_type(4))) float f32x4;

__device__ __forceinline__ float bf2f(unsigned short u) {
  return __uint_as_float(((unsigned int)u) << 16);
}
__device__ __forceinline__ unsigned short f2bf(float f) {
  unsigned int u = __float_as_uint(f);
  u += 0x7fffu + ((u >> 16) & 1u);
  return (unsigned short)(u >> 16);
}

// ---------------- workspace layout (bytes) ----------------
constexpr size_t OFF_XPAD = 0;
constexpr size_t SZ_XPAD  = (size_t)8 * 66 * 66 * 128 * 2;        // 8,921,088
constexpr size_t OFF_WB   = OFF_XPAD + SZ_XPAD;
constexpr size_t SZ_WB    = (size_t)9 * 16 * 256 * 8 * 2;         // 589,824
constexpr size_t OFF_WS2  = OFF_WB + SZ_WB;
constexpr size_t SZ_WS2   = (size_t)16 * 256 * 8 * 2;             // 65,536
constexpr size_t OFF_WO   = OFF_WS2 + SZ_WS2;
constexpr size_t SZ_WO    = (size_t)9 * 16 * 32 * 8 * 2;          // 73,728
// y_main bf16 [32768][256]
constexpr size_t OFF_YM   = OFF_WO + SZ_WO;
constexpr size_t SZ_YM    = (size_t)32768 * 256 * 2;              // 16,777,216
constexpr size_t OFF_SR   = OFF_YM + SZ_YM;                        // statsRaw [8][256][2] f32
constexpr size_t SZ_SR    = (size_t)8 * 256 * 2 * 4;              // 16,384

// XCD swizzle: xcd = blockIdx.x % 8 (round-robin). b = blk&7 -> batch b lands on
// XCD b; per-XCD L2 working set = 1 batch xpad (1.1MB) + wB (0.58MB). Verified R2:
// FETCH_SIZE 26.4MB -> 7.3MB.
// BN stats: k_main atomicAdds per-batch partials into statsRaw (zeroed by k_prep);
// k_final finalizes per-block from the 16KB buffer. Removes k_stats dispatch + 1MB
// partials round-trip. (Cooperative grid.sync fusion failed to launch in harness - R5.)

// ---------------- fused prep: x transpose (0..511) + weight pack (512..1935) + stats zero (1936) ----------------
__global__ __launch_bounds__(256) void k_prep(const float* __restrict__ x,
                                              unsigned short* __restrict__ xp,
                                              const float* __restrict__ wdef,
                                              const float* __restrict__ wsc,
                                              const float* __restrict__ woff,
                                              unsigned short* __restrict__ wB,
                                              unsigned short* __restrict__ wS,
                                              unsigned short* __restrict__ wO,
                                              float* __restrict__ statsRaw) {
  int t = threadIdx.x;
  if (blockIdx.x == 1936) {           // zero BN accumulators (graph-replay safe)
    for (int i = t; i < 4096; i += 256) statsRaw[i] = 0.f;
    return;
  }
  if (blockIdx.x >= 512) {            // ---- weight packing part ----
    int tid = (blockIdx.x - 512) * 256 + t;
    if (tid < 294912) {
      int k8 = tid & 7, n = (tid >> 3) & 255, kb = (tid >> 11) & 15, tap = tid >> 15;
      int c = kb * 8 + k8;
      wB[tid] = f2bf(wdef[((size_t)n * 128 + c) * 9 + tap]);
    } else if (tid < 294912 + 32768) {
      int i = tid - 294912;
      int k8 = i & 7, n = (i >> 3) & 255, kb = i >> 11;
      wS[i] = f2bf(wsc[(size_t)n * 128 + kb * 8 + k8]);
    } else if (tid < 294912 + 32768 + 36864) {
      int i = tid - 327680;
      int k8 = i & 7, n = (i >> 3) & 31, kb = (i >> 8) & 15, tap = i >> 12;
      int c = kb * 8 + k8;
      wO[i] = f2bf(n < 18 ? woff[((size_t)n * 128 + c) * 9 + tap] : 0.f);
    }
    return;
  }
  // ---- x: NCHW fp32 -> NHWC bf16 zero-padded (+ halo zeroing, no memset) ----
  int blk = blockIdx.x;               // 512; b = blk&7 (XCD-local), h = blk>>3
  int b = blk & 7, h = blk >> 3;
  __shared__ unsigned short xt[128 * 68];   // [c][w], stride 68
  {
    unsigned short* base = xp + (size_t)b * 66 * 66 * 128;
    ushort4 z4 = {0, 0, 0, 0};
    if (t < 64) {                     // side columns of padded row h+1
      int col = (t >> 5) ? 65 : 0;
      int i = t & 31;
      *(ushort4*)(base + ((size_t)(h + 1) * 66 + col) * 128 + i * 4) = z4;
    }
    if (h == 0) {                     // top and bottom padded rows
      for (int i = t; i < 2112; i += 256) {
        *(ushort4*)(base + (size_t)i * 4) = z4;
        *(ushort4*)(base + (size_t)65 * 66 * 128 + (size_t)i * 4) = z4;
      }
    }
  }
  {
    int c = t >> 1, w0 = (t & 1) * 32;
    const float4* xs = (const float4*)&x[(((size_t)b * 128 + c) * 64 + h) * 64 + w0];
    unsigned short* row = &xt[c * 68 + w0];
#pragma unroll
    for (int i4 = 0; i4 < 8; ++i4) {
      float4 f = xs[i4];
      ushort4 u4;
      u4.x = f2bf(f.x); u4.y = f2bf(f.y); u4.z = f2bf(f.z); u4.w = f2bf(f.w);
      *(ushort4*)(row + i4 * 4) = u4;
    }
  }
  __syncthreads();
  {
    int w = t >> 2, c0 = (t & 3) * 32;
    unsigned short tmp[32];
#pragma unroll
    for (int i = 0; i < 32; ++i) tmp[i] = xt[(c0 + i) * 68 + w];
    unsigned short* dst = xp + ((size_t)(b * 66 + h + 1) * 66 + (w + 1)) * 128 + c0;
#pragma unroll
    for (int i8 = 0; i8 < 4; ++i8)
      *(bf16x8*)(dst + i8 * 8) = *(const bf16x8*)&tmp[i8 * 8];
  }
}

// ---------------- main: offset conv + deform-sample + 3x3 conv GEMM + BN atomics ----------------
// 512 blocks x 512 thr (8 waves); Breg preload keeps MFMA off the vmcnt FIFO chain.
__global__ __launch_bounds__(512, 4) void k_main(const unsigned short* __restrict__ xp,
                                                 const unsigned short* __restrict__ wB,
                                                 const unsigned short* __restrict__ wO,
                                                 const float* __restrict__ boff,
                                                 const float* __restrict__ bdef,
                                                 unsigned short* __restrict__ ymain,
                                                 float* __restrict__ statsRaw) {
  int blk = blockIdx.x;               // 512; b = blk&7 (XCD-local), h = blk>>3
  int b = blk & 7, h = blk >> 3;
  int bh = (b << 6) + h;              // linear row id for ymain layout
  int t = threadIdx.x;
  int lane = t & 63, wid = t >> 6;    // 8 waves
  int m = lane & 15, quad = lane >> 4;
  __shared__ __align__(16) unsigned short At[2][64 * 136];  // 2 x 17408 B
  __shared__ float offsL[9][64][2];                          // 4608 B

  // ---- phase 0: inline offset conv (waves 0-3 compute this row's 18 offsets -> LDS) ----
  if (wid < 4) {
    f32x4 a0 = {0.f, 0.f, 0.f, 0.f}, a1 = {0.f, 0.f, 0.f, 0.f};
    int px = wid * 16 + m;
    const unsigned short* xbase = xp + ((size_t)(b * 66 + h) * 66 + px) * 128 + quad * 8;
    for (int tap = 0; tap < 9; ++tap) {
      const unsigned short* arow = xbase + ((tap / 3) * 66 + (tap % 3)) * 128;
#pragma unroll
      for (int kk = 0; kk < 4; ++kk) {
        bf16x8 a = *(const bf16x8*)(arow + kk * 32);
        const unsigned short* bb = wO + (size_t)(tap * 16 + kk * 4 + quad) * 256;
        bf16x8 b0 = *(const bf16x8*)(bb + m * 8);
        bf16x8 b1 = *(const bf16x8*)(bb + (16 + m) * 8);
        a0 = __builtin_amdgcn_mfma_f32_16x16x32_bf16(a, b0, a0, 0, 0, 0);
        a1 = __builtin_amdgcn_mfma_f32_16x16x32_bf16(a, b1, a1, 0, 0, 0);
      }
    }
#pragma unroll
    for (int r = 0; r < 4; ++r) {
      int pxs = wid * 16 + quad * 4 + r;
      offsL[m >> 1][pxs][m & 1] = a0[r] + boff[m];   // n=m in [0,16): tap=n>>1, comp=n&1
      if (m < 2) offsL[8][pxs][m] = a1[r] + boff[16 + m];
    }
  }

  f32x4 acc[4][2];
#pragma unroll
  for (int i = 0; i < 4; ++i)
#pragma unroll
    for (int j = 0; j < 2; ++j) acc[i][j] = (f32x4){0.f, 0.f, 0.f, 0.f};

  // sampling role: thread = px_s*8 + sub; 8 consecutive lanes cover one 128B chunk
  int px_s = t >> 3, sub = t & 7;
  const unsigned short* xb_base = xp + (size_t)b * 66 * 66 * 128;
  int nb = wid * 32;                  // mfma role: 32-ch N slice per wave, M=64 shared

  bf16x8 Breg[4][2];                  // this tap's wB fragments, preloaded
  auto loadB = [&](int tap) {
#pragma unroll
    for (int kk = 0; kk < 4; ++kk)
#pragma unroll
      for (int ns = 0; ns < 2; ++ns)
        Breg[kk][ns] = *(const bf16x8*)(wB + ((size_t)(tap * 16 + kk * 4 + quad) * 256 + nb + ns * 16 + m) * 8);
  };

  auto sample_prep = [&](int tap, float* wgt, const unsigned short** p) {
    float2 ov = *(const float2*)&offsL[tap][px_s][0];
    int ky = tap / 3 - 1, kx = tap % 3 - 1;
    float py = (float)(h + ky) + ov.x;
    float pxf = (float)(px_s + kx) + ov.y;
    float y0f = floorf(py), x0f = floorf(pxf);
    float fy = py - y0f, fx = pxf - x0f;
    int iy0 = (int)y0f, ix0 = (int)x0f;
#pragma unroll
    for (int j = 0; j < 4; ++j) {
      int iy = iy0 + (j >> 1), ix = ix0 + (j & 1);
      float wy = (j >> 1) ? fy : 1.f - fy;
      float wx = (j & 1) ? fx : 1.f - fx;
      bool valid = (iy >= 0) && (iy < 64) && (ix >= 0) && (ix < 64);
      int iyc = min(max(iy, 0), 63), ixc = min(max(ix, 0), 63);
      wgt[j] = valid ? wy * wx : 0.f;
      p[j] = xb_base + ((size_t)(iyc + 1) * 66 + (ixc + 1)) * 128 + sub * 8;
    }
  };
  auto load_g1 = [&](const unsigned short** p, int g, bf16x8* v) {
#pragma unroll
    for (int j = 0; j < 4; ++j)
      v[j] = *(const bf16x8*)(p[j] + g * 64);
  };
  auto store_g1 = [&](unsigned short* dst, int g, const float* wgt, bf16x8* v) {
    bf16x8 o;
#pragma unroll
    for (int j = 0; j < 8; ++j) {
      float s = fmaf(wgt[0], bf2f((unsigned short)v[0][j]),
                fmaf(wgt[1], bf2f((unsigned short)v[1][j]),
                fmaf(wgt[2], bf2f((unsigned short)v[2][j]),
                     wgt[3] * bf2f((unsigned short)v[3][j]))));
      o[j] = (short)f2bf(s);
    }
    *(bf16x8*)(dst + g * 64) = o;
  };
  auto mfma_half = [&](const unsigned short* buf, int kk0) {
#pragma unroll
    for (int kk = kk0; kk < kk0 + 2; ++kk) {
      bf16x8 af[4];
#pragma unroll
      for (int ms = 0; ms < 4; ++ms)
        af[ms] = *(const bf16x8*)(buf + (ms * 16 + m) * 136 + kk * 32 + quad * 8);
#pragma unroll
      for (int ns = 0; ns < 2; ++ns)
#pragma unroll
        for (int ms = 0; ms < 4; ++ms)
          acc[ms][ns] = __builtin_amdgcn_mfma_f32_16x16x32_bf16(af[ms], Breg[kk][ns], acc[ms][ns], 0, 0, 0);
    }
  };

  // prologue: B-frags for tap 0, then sample tap 0 into buf 0
  loadB(0);
  __syncthreads();                    // offsL ready
  {
    float wgt[4]; const unsigned short* p[4]; bf16x8 v0[4], v1[4];
    sample_prep(0, wgt, p);
    unsigned short* dst = &At[0][px_s * 136 + sub * 8];
    load_g1(p, 0, v0); load_g1(p, 1, v1);
    store_g1(dst, 0, wgt, v0); store_g1(dst, 1, wgt, v1);
  }
#pragma unroll
  for (int tap = 0; tap < 9; ++tap) {
    __syncthreads();
    const unsigned short* cur = At[tap & 1];
    unsigned short* dst = &At[(tap + 1) & 1][px_s * 136 + sub * 8];
    if (tap < 8) {
      float wgt[4]; const unsigned short* p[4]; bf16x8 v0[4], v1[4];
      sample_prep(tap + 1, wgt, p);
      load_g1(p, 0, v0);
      load_g1(p, 1, v1);
      mfma_half(cur, 0);              // regs + ds_read only: no vmcnt dependence
      store_g1(dst, 0, wgt, v0);
      mfma_half(cur, 2);
      loadB(tap + 1);                 // prefetch next tap's B
      store_g1(dst, 1, wgt, v1);
    } else {
      mfma_half(cur, 0);
      mfma_half(cur, 2);
    }
  }

  // ---- epilogue: bias + BN atomics; LDS transpose -> coalesced bf16 stores ----
  __syncthreads();                    // all waves done reading At
  unsigned short* yb = &At[0][0];     // 64 x 264 bf16 (33792 B)
#pragma unroll
  for (int ns = 0; ns < 2; ++ns) {
    int n = nb + ns * 16 + m;
    float bias = bdef[n];
    float s = 0.f, q = 0.f;
#pragma unroll
    for (int ms = 0; ms < 4; ++ms) {
#pragma unroll
      for (int r = 0; r < 4; ++r) {
        int px = ms * 16 + quad * 4 + r;
        float v = acc[ms][ns][r] + bias;
        yb[px * 264 + n] = f2bf(v);
        s += v;
        q += v * v;
      }
    }
    s += __shfl_xor(s, 16); s += __shfl_xor(s, 32);
    q += __shfl_xor(q, 16); q += __shfl_xor(q, 32);
    if (quad == 0) {                  // 64 blocks share each address (batch-local)
      atomicAdd(&statsRaw[((size_t)b * 256 + n) * 2 + 0], s);
      atomicAdd(&statsRaw[((size_t)b * 256 + n) * 2 + 1], q);
    }
  }
  __syncthreads();
  {
    unsigned short* grow = ymain + (size_t)(bh * 64 + px_s) * 256;
    const unsigned short* lrow = yb + px_s * 264;
#pragma unroll
    for (int k = 0; k < 4; ++k) {
      int n0 = k * 64 + sub * 8;      // 8 consecutive lanes -> one 128B chunk
      __builtin_nontemporal_store(*(const bf16x8*)(lrow + n0), (bf16x8*)(grow + n0));
    }
  }
}

// ---------------- final: stats finalize + 1x1 shortcut MFMA + BN apply + ReLU + NCHW store ----------------
// 1024 blocks x 32-px tiles; batch->XCD swizzle; per-block stats finalize from 16KB statsRaw.
__global__ __launch_bounds__(256) void k_final(const unsigned short* __restrict__ xp,
                                               const unsigned short* __restrict__ wS,
                                               const unsigned short* __restrict__ ymain,
                                               const float* __restrict__ statsRaw,
                                               const float* __restrict__ gamma,
                                               const float* __restrict__ beta,
                                               const float* __restrict__ bsc,
                                               float* __restrict__ out) {
  int blk = blockIdx.x;               // 1024; b = blk&7 (XCD-local)
  int b = blk & 7, rem = blk >> 3, h = rem >> 1, half = rem & 1;
  int px0 = half * 32;
  int bh = (b << 6) + h;
  int t = threadIdx.x;
  int lane = t & 63, wid = t >> 6;
  int m = lane & 15, quad = lane >> 4;
  __shared__ float tr[128 * 35];      // 17,920 B
  __shared__ float sAB[512];          // [0:256) scale, [256:512) shift
  // phase 0: stats finalize (cheap: 8 adds/channel from 16KB buffer)
  {
    float s = 0.f, q = 0.f;
#pragma unroll
    for (int i = 0; i < 8; ++i) {
      float2 pq = *(const float2*)&statsRaw[((size_t)i * 256 + t) * 2];
      s += pq.x;
      q += pq.y;
    }
    float mean = s * (1.f / 32768.f);
    float var = q * (1.f / 32768.f) - mean * mean;
    float inv = rsqrtf(var + 1e-5f);
    float A = gamma[t] * inv;
    sAB[t] = A;
    sAB[256 + t] = beta[t] - mean * A;
  }
  f32x4 acc[2][4];
#pragma unroll
  for (int i = 0; i < 2; ++i)
#pragma unroll
    for (int j = 0; j < 4; ++j) acc[i][j] = (f32x4){0.f, 0.f, 0.f, 0.f};
  const unsigned short* xrow = xp + ((size_t)(b * 66 + h + 1) * 66 + 1 + px0) * 128;
  int nb = wid * 64;
#pragma unroll
  for (int kk = 0; kk < 4; ++kk) {
    bf16x8 af[2];
#pragma unroll
    for (int ms = 0; ms < 2; ++ms)
      af[ms] = *(const bf16x8*)(xrow + (ms * 16 + m) * 128 + kk * 32 + quad * 8);
#pragma unroll
    for (int ns = 0; ns < 4; ++ns) {
      bf16x8 bfr = *(const bf16x8*)(wS + ((size_t)(kk * 4 + quad) * 256 + nb + ns * 16 + m) * 8);
#pragma unroll
      for (int ms = 0; ms < 2; ++ms)
        acc[ms][ns] = __builtin_amdgcn_mfma_f32_16x16x32_bf16(af[ms], bfr, acc[ms][ns], 0, 0, 0);
    }
  }
  __syncthreads();                    // sAB ready (also covers tr reuse below)
  for (int pass = 0; pass < 2; ++pass) {
    if ((wid >> 1) == pass) {
#pragma unroll
      for (int ns = 0; ns < 4; ++ns) {
        int n = nb + ns * 16 + m;
        float bs = bsc[n];
        int nl = n - pass * 128;
#pragma unroll
        for (int ms = 0; ms < 2; ++ms)
#pragma unroll
          for (int r = 0; r < 4; ++r) {
            int px = ms * 16 + quad * 4 + r;
            tr[nl * 35 + px] = acc[ms][ns][r] + bs;
          }
      }
    }
    __syncthreads();
    {
      int nl2 = t & 63, g = t >> 6;
      int n = pass * 128 + nl2 * 2;
      float A0 = sAB[n], B0 = sAB[256 + n];
      float A1 = sAB[n + 1], B1 = sAB[256 + n + 1];
#pragma unroll
      for (int i = 0; i < 8; ++i) {
        int pxl = g * 8 + i;
        unsigned int ym2 = *(const unsigned int*)(ymain + (size_t)(bh * 64 + px0 + pxl) * 256 + n);
        float y0 = bf2f((unsigned short)(ym2 & 0xffffu));
        float y1 = bf2f((unsigned short)(ym2 >> 16));
        int nl = nl2 * 2;
        float* p0 = &tr[nl * 35 + pxl];
        float* p1 = &tr[(nl + 1) * 35 + pxl];
        *p0 = fmaxf(fmaf(y0, A0, B0) + *p0, 0.f);
        *p1 = fmaxf(fmaf(y1, A1, B1) + *p1, 0.f);
      }
    }
    __syncthreads();
    {
      int ww = t & 31, ng = t >> 5;
#pragma unroll
      for (int i = 0; i < 16; ++i) {
        int nl = ng * 16 + i;
        out[((size_t)(b * 256 + pass * 128 + nl) * 64 + h) * 64 + px0 + ww] = tr[nl * 35 + ww];
      }
    }
    __syncthreads();
  }
}

extern "C" void kernel_launch(void* const* d_in, const int* in_sizes, int n_in,
                              void* d_out, int out_size, void* d_ws, size_t ws_size,
                              hipStream_t stream) {
  const float* x     = (const float*)d_in[0];
  const float* w_off = (const float*)d_in[1];
  const float* b_off = (const float*)d_in[2];
  const float* w_def = (const float*)d_in[3];
  const float* b_def = (const float*)d_in[4];
  const float* gamma = (const float*)d_in[5];
  const float* beta  = (const float*)d_in[6];
  const float* w_sc  = (const float*)d_in[7];
  const float* b_sc  = (const float*)d_in[8];
  float* out = (float*)d_out;

  char* ws = (char*)d_ws;
  unsigned short* xpad  = (unsigned short*)(ws + OFF_XPAD);
  unsigned short* wB    = (unsigned short*)(ws + OFF_WB);
  unsigned short* wS    = (unsigned short*)(ws + OFF_WS2);
  unsigned short* wO    = (unsigned short*)(ws + OFF_WO);
  unsigned short* ymain = (unsigned short*)(ws + OFF_YM);
  float* statsRaw       = (float*)(ws + OFF_SR);

  k_prep<<<1937, 256, 0, stream>>>(x, xpad, w_def, w_sc, w_off, wB, wS, wO, statsRaw);
  k_main<<<512, 512, 0, stream>>>(xpad, wB, wO, b_off, b_def, ymain, statsRaw);
  k_final<<<1024, 256, 0, stream>>>(xpad, wS, ymain, statsRaw, gamma, beta, b_sc, out);
}